// Round 1
// baseline (810.595 us; speedup 1.0000x reference)
//
#include <hip/hip_runtime.h>

// Problem constants (fixed by the reference file)
#define NODES_C 65536   // N*N, N=256
#define B_C     16
#define E_C     1048576 // NODES*16
#define K_C     5

// ---------------------------------------------------------------------------
// Kernel 1: per-edge weight w[e] = dot(dist[e,:], coeffs) + histogram of dst
// grid = E/256 exactly
__global__ __launch_bounds__(256) void k_prep(
    const float* __restrict__ dist, const float* __restrict__ coeffs,
    const int* __restrict__ dst, float* __restrict__ w, int* __restrict__ counts)
{
    int e = blockIdx.x * 256 + threadIdx.x;
    float c0 = coeffs[0], c1 = coeffs[1], c2 = coeffs[2], c3 = coeffs[3], c4 = coeffs[4];
    const float* d = dist + (size_t)e * K_C;
    float v = d[0]*c0 + d[1]*c1 + d[2]*c2 + d[3]*c3 + d[4]*c4;
    w[e] = v;
    atomicAdd(&counts[dst[e]], 1);
}

// ---------------------------------------------------------------------------
// Kernel 2: single-block exclusive prefix sum over counts[NODES] -> row_start
// Also copies the exclusive prefix into fill_pos for the scatter pass.
// 1024 threads, each owns 64 consecutive entries.
__global__ __launch_bounds__(1024) void k_scan(
    int* __restrict__ row_start /* counts in, exclusive prefix out */,
    int* __restrict__ fill_pos)
{
    __shared__ int sdata[1024];
    int t = threadIdx.x;
    int base = t * 64;

    int s = 0;
    for (int j = 0; j < 64; ++j) s += row_start[base + j];
    sdata[t] = s;
    __syncthreads();

    // Hillis-Steele inclusive scan over 1024 partials
    for (int off = 1; off < 1024; off <<= 1) {
        int v   = sdata[t];
        int add = (t >= off) ? sdata[t - off] : 0;
        __syncthreads();
        sdata[t] = v + add;
        __syncthreads();
    }
    int run = (t == 0) ? 0 : sdata[t - 1];

    for (int j = 0; j < 64; ++j) {
        int c = row_start[base + j];
        row_start[base + j] = run;
        fill_pos[base + j]  = run;
        run += c;
    }
    if (t == 1023) row_start[NODES_C] = run;  // == E
}

// ---------------------------------------------------------------------------
// Kernel 3: scatter edges into CSR order (by dst)
__global__ __launch_bounds__(256) void k_scatter(
    const int* __restrict__ src, const int* __restrict__ dst,
    const float* __restrict__ w, int* __restrict__ fill_pos,
    int* __restrict__ csr_src, float* __restrict__ csr_w)
{
    int e = blockIdx.x * 256 + threadIdx.x;
    int d = dst[e];
    int p = atomicAdd(&fill_pos[d], 1);
    csr_src[p] = src[e];
    csr_w[p]   = w[e];
}

// ---------------------------------------------------------------------------
// Kernel 4: transpose input x [B][N] -> node-major x0 [N][B]
__global__ __launch_bounds__(256) void k_transpose(
    const float* __restrict__ x_in, float* __restrict__ x_node)
{
    int tid = blockIdx.x * 256 + threadIdx.x;   // tid = b*N + n
    int b = tid >> 16;                          // N = 65536 = 2^16
    int n = tid & 0xFFFF;
    x_node[((size_t)n << 4) + b] = x_in[tid];
}

// ---------------------------------------------------------------------------
// Kernel 5: one explicit-Euler step.
// thread = (node, batch); node-group = 16 consecutive lanes sharing the CSR row.
// Writes node-major state for the next step + batch-major slice of out[:, t, :].
__global__ __launch_bounds__(256) void k_step(
    const int* __restrict__ row_start, const int* __restrict__ csr_src,
    const float* __restrict__ csr_w, const float* __restrict__ x_cur,
    float* __restrict__ x_next, float* __restrict__ out,
    const float* __restrict__ dt_p, size_t TN, int tstep)
{
    __shared__ float tile[16][17];
    int tid = blockIdx.x * 256 + threadIdx.x;
    int n = tid >> 4;
    int b = tid & 15;

    int r0 = row_start[n];
    int r1 = row_start[n + 1];
    float acc = 0.f;
    for (int i = r0; i < r1; ++i) {
        acc = fmaf(csr_w[i], x_cur[((size_t)csr_src[i] << 4) + b], acc);
    }
    float xn = fmaf(dt_p[0], acc, x_cur[((size_t)n << 4) + b]);
    x_next[((size_t)n << 4) + b] = xn;

    // LDS transpose so the out[] store is 64B-coalesced per 16-lane group
    int ln = threadIdx.x >> 4;      // local node 0..15
    tile[ln][b] = xn;
    __syncthreads();
    int wb = threadIdx.x >> 4;      // batch for the write phase
    int wn = threadIdx.x & 15;      // local node for the write phase
    int n0 = blockIdx.x * 16;
    out[(size_t)wb * TN + (size_t)tstep * NODES_C + n0 + wn] = tile[wn][wb];
}

// ---------------------------------------------------------------------------
extern "C" void kernel_launch(void* const* d_in, const int* in_sizes, int n_in,
                              void* d_out, int out_size, void* d_ws, size_t ws_size,
                              hipStream_t stream)
{
    const float* x_in   = (const float*)d_in[0];
    // d_in[1] = points (unused by the reference computation)
    const int*   eidx   = (const int*)d_in[2];
    const float* dt_p   = (const float*)d_in[3];
    // d_in[4] = num_blocks (T derived from out_size instead)
    const float* dist   = (const float*)d_in[5];
    const float* coeffs = (const float*)d_in[6];

    const int* src = eidx;          // edge_index[0]
    const int* dst = eidx + E_C;    // edge_index[1]
    float* out = (float*)d_out;

    // workspace layout (needs ~21 MB)
    char* ws = (char*)d_ws;
    float* w         = (float*)(ws + 0);                           // 4 MB
    int*   row_start = (int*)  (ws + (4u  << 20));                 // 256 KB + 4
    int*   fill_pos  = (int*)  (ws + (4u  << 20) + (512u << 10));  // 256 KB
    int*   csr_src   = (int*)  (ws + (5u  << 20));                 // 4 MB
    float* csr_w     = (float*)(ws + (9u  << 20));                 // 4 MB
    float* x0        = (float*)(ws + (13u << 20));                 // 4 MB
    float* x1        = (float*)(ws + (17u << 20));                 // 4 MB

    int T = out_size / (B_C * NODES_C);          // = 20
    size_t TN = (size_t)T * NODES_C;

    hipMemsetAsync(row_start, 0, (NODES_C + 1) * sizeof(int), stream);
    k_prep   <<<E_C / 256, 256, 0, stream>>>(dist, coeffs, dst, w, row_start);
    k_scan   <<<1, 1024, 0, stream>>>(row_start, fill_pos);
    k_scatter<<<E_C / 256, 256, 0, stream>>>(src, dst, w, fill_pos, csr_src, csr_w);
    k_transpose<<<(NODES_C * B_C) / 256, 256, 0, stream>>>(x_in, x0);

    float* bufs[2] = { x0, x1 };
    for (int t = 0; t < T; ++t) {
        k_step<<<(NODES_C * B_C) / 256, 256, 0, stream>>>(
            row_start, csr_src, csr_w, bufs[t & 1], bufs[(t + 1) & 1],
            out, dt_p, TN, t);
    }
}

// Round 2
// 489.271 us; speedup vs baseline: 1.6567x; 1.6567x over previous
//
#include <hip/hip_runtime.h>

// Problem constants (fixed by the reference file)
#define NODES_C 65536   // N*N, N=256
#define B_C     16
#define E_C     1048576 // NODES*16
#define K_C     5

typedef unsigned long long u64;

// ---------------------------------------------------------------------------
// Kernel 1: histogram of dst
__global__ __launch_bounds__(256) void k_count(
    const int* __restrict__ dst, int* __restrict__ counts)
{
    int e = blockIdx.x * 256 + threadIdx.x;
    atomicAdd(&counts[dst[e]], 1);
}

// ---------------------------------------------------------------------------
// Kernel 2: single-block exclusive prefix sum over counts[NODES] -> row_start
// Also copies the exclusive prefix into fill_pos for the scatter pass.
__global__ __launch_bounds__(1024) void k_scan(
    int* __restrict__ row_start /* counts in, exclusive prefix out */,
    int* __restrict__ fill_pos)
{
    __shared__ int sdata[1024];
    int t = threadIdx.x;
    int base = t * 64;

    int s = 0;
    for (int j = 0; j < 64; ++j) s += row_start[base + j];
    sdata[t] = s;
    __syncthreads();

    for (int off = 1; off < 1024; off <<= 1) {
        int v   = sdata[t];
        int add = (t >= off) ? sdata[t - off] : 0;
        __syncthreads();
        sdata[t] = v + add;
        __syncthreads();
    }
    int run = (t == 0) ? 0 : sdata[t - 1];

    for (int j = 0; j < 64; ++j) {
        int c = row_start[base + j];
        row_start[base + j] = run;
        fill_pos[base + j]  = run;
        run += c;
    }
    if (t == 1023) row_start[NODES_C] = run;  // == E
}

// ---------------------------------------------------------------------------
// Kernel 3: compute w[e] = dot(dist,coeffs) and scatter packed {src,w} into
// CSR order (by dst). One 8B store per edge.
__global__ __launch_bounds__(256) void k_scatter(
    const int* __restrict__ src, const int* __restrict__ dst,
    const float* __restrict__ dist, const float* __restrict__ coeffs,
    int* __restrict__ fill_pos, u64* __restrict__ csr)
{
    int e = blockIdx.x * 256 + threadIdx.x;
    float c0 = coeffs[0], c1 = coeffs[1], c2 = coeffs[2], c3 = coeffs[3], c4 = coeffs[4];
    const float* d = dist + (size_t)e * K_C;
    float wv = d[0]*c0 + d[1]*c1 + d[2]*c2 + d[3]*c3 + d[4]*c4;
    int p = atomicAdd(&fill_pos[dst[e]], 1);
    u64 packed = ((u64)__float_as_uint(wv) << 32) | (unsigned)src[e];
    csr[p] = packed;
}

// ---------------------------------------------------------------------------
// Kernel 4: transpose input x [B][N] -> node-major x0 [N][B]
__global__ __launch_bounds__(256) void k_transpose(
    const float* __restrict__ x_in, float* __restrict__ x_node)
{
    int tid = blockIdx.x * 256 + threadIdx.x;   // tid = b*N + n
    int b = tid >> 16;                          // N = 65536 = 2^16
    int n = tid & 0xFFFF;
    x_node[((size_t)n << 4) + b] = x_in[tid];
}

// ---------------------------------------------------------------------------
// Kernel 5: one explicit-Euler step.
// thread = (node, quad q): handles batches 4q..4q+3 as a float4 accumulator.
// 4 independent FMA chains per thread, 2 edges in flight (hand-unroll x2).
__global__ __launch_bounds__(256) void k_step(
    const int* __restrict__ row_start, const u64* __restrict__ csr,
    const float* __restrict__ x_cur, float* __restrict__ x_next,
    float* __restrict__ out, const float* __restrict__ dt_p,
    size_t TN, int tstep)
{
    __shared__ float tile[64][17];
    int tid = blockIdx.x * 256 + threadIdx.x;
    int n = tid >> 2;
    int q = tid & 3;

    int r0 = row_start[n];
    int r1 = row_start[n + 1];
    float ax = 0.f, ay = 0.f, az = 0.f, aw = 0.f;

    int i = r0;
    for (; i + 1 < r1; i += 2) {
        u64 e0 = csr[i];
        u64 e1 = csr[i + 1];
        int   s0 = (int)(unsigned)e0;
        float w0 = __uint_as_float((unsigned)(e0 >> 32));
        int   s1 = (int)(unsigned)e1;
        float w1 = __uint_as_float((unsigned)(e1 >> 32));
        float4 v0 = *(const float4*)(x_cur + (((size_t)s0) << 4) + (q << 2));
        float4 v1 = *(const float4*)(x_cur + (((size_t)s1) << 4) + (q << 2));
        ax = fmaf(w0, v0.x, ax); ay = fmaf(w0, v0.y, ay);
        az = fmaf(w0, v0.z, az); aw = fmaf(w0, v0.w, aw);
        ax = fmaf(w1, v1.x, ax); ay = fmaf(w1, v1.y, ay);
        az = fmaf(w1, v1.z, az); aw = fmaf(w1, v1.w, aw);
    }
    if (i < r1) {
        u64 e0 = csr[i];
        int   s0 = (int)(unsigned)e0;
        float w0 = __uint_as_float((unsigned)(e0 >> 32));
        float4 v0 = *(const float4*)(x_cur + (((size_t)s0) << 4) + (q << 2));
        ax = fmaf(w0, v0.x, ax); ay = fmaf(w0, v0.y, ay);
        az = fmaf(w0, v0.z, az); aw = fmaf(w0, v0.w, aw);
    }

    float dt = dt_p[0];
    float4 xo = *(const float4*)(x_cur + (((size_t)n) << 4) + (q << 2));
    xo.x = fmaf(dt, ax, xo.x);
    xo.y = fmaf(dt, ay, xo.y);
    xo.z = fmaf(dt, az, xo.z);
    xo.w = fmaf(dt, aw, xo.w);
    *(float4*)(x_next + (((size_t)n) << 4) + (q << 2)) = xo;

    // LDS transpose: 64 nodes x 16 batches -> coalesced out writes
    int ln = threadIdx.x >> 2;            // local node 0..63
    int c0i = q << 2;
    tile[ln][c0i + 0] = xo.x;
    tile[ln][c0i + 1] = xo.y;
    tile[ln][c0i + 2] = xo.z;
    tile[ln][c0i + 3] = xo.w;
    __syncthreads();
    int wb  = threadIdx.x >> 4;           // batch 0..15
    int wn0 = (threadIdx.x & 15) << 2;    // local node 0,4,..,60
    int n0  = blockIdx.x * 64;
    float4 ov;
    ov.x = tile[wn0 + 0][wb];
    ov.y = tile[wn0 + 1][wb];
    ov.z = tile[wn0 + 2][wb];
    ov.w = tile[wn0 + 3][wb];
    *(float4*)(out + (size_t)wb * TN + (size_t)tstep * NODES_C + n0 + wn0) = ov;
}

// ---------------------------------------------------------------------------
extern "C" void kernel_launch(void* const* d_in, const int* in_sizes, int n_in,
                              void* d_out, int out_size, void* d_ws, size_t ws_size,
                              hipStream_t stream)
{
    const float* x_in   = (const float*)d_in[0];
    // d_in[1] = points (unused by the reference computation)
    const int*   eidx   = (const int*)d_in[2];
    const float* dt_p   = (const float*)d_in[3];
    // d_in[4] = num_blocks (T derived from out_size instead)
    const float* dist   = (const float*)d_in[5];
    const float* coeffs = (const float*)d_in[6];

    const int* src = eidx;          // edge_index[0]
    const int* dst = eidx + E_C;    // edge_index[1]
    float* out = (float*)d_out;

    // workspace layout (~17 MB)
    char* ws = (char*)d_ws;
    int*   row_start = (int*)(ws + 0);                    // 256 KB + 4
    int*   fill_pos  = (int*)(ws + (512u << 10));         // 256 KB
    u64*   csr       = (u64*)(ws + (1u  << 20));          // 8 MB
    float* x0        = (float*)(ws + (9u  << 20));        // 4 MB
    float* x1        = (float*)(ws + (13u << 20));        // 4 MB

    int T = out_size / (B_C * NODES_C);          // = 20
    size_t TN = (size_t)T * NODES_C;

    hipMemsetAsync(row_start, 0, (NODES_C + 1) * sizeof(int), stream);
    k_count  <<<E_C / 256, 256, 0, stream>>>(dst, row_start);
    k_scan   <<<1, 1024, 0, stream>>>(row_start, fill_pos);
    k_scatter<<<E_C / 256, 256, 0, stream>>>(src, dst, dist, coeffs, fill_pos, csr);
    k_transpose<<<(NODES_C * B_C) / 256, 256, 0, stream>>>(x_in, x0);

    float* bufs[2] = { x0, x1 };
    for (int t = 0; t < T; ++t) {
        k_step<<<(NODES_C * B_C / 4) / 256, 256, 0, stream>>>(
            row_start, csr, bufs[t & 1], bufs[(t + 1) & 1],
            out, dt_p, TN, t);
    }
}

// Round 3
// 432.983 us; speedup vs baseline: 1.8721x; 1.1300x over previous
//
#include <hip/hip_runtime.h>

// Problem constants (fixed by the reference file)
#define NODES_C 65536   // N*N, N=256
#define B_C     16
#define E_C     1048576 // NODES*16
#define K_C     5

typedef unsigned long long u64;

// ---------------------------------------------------------------------------
// Kernel 1: histogram of dst
__global__ __launch_bounds__(256) void k_count(
    const int* __restrict__ dst, int* __restrict__ counts)
{
    int e = blockIdx.x * 256 + threadIdx.x;
    atomicAdd(&counts[dst[e]], 1);
}

// ---------------------------------------------------------------------------
// Kernel 2: single-block exclusive prefix sum over counts[NODES] -> row_start
__global__ __launch_bounds__(1024) void k_scan(
    int* __restrict__ row_start /* counts in, exclusive prefix out */,
    int* __restrict__ fill_pos)
{
    __shared__ int sdata[1024];
    int t = threadIdx.x;
    int base = t * 64;

    int s = 0;
    for (int j = 0; j < 64; ++j) s += row_start[base + j];
    sdata[t] = s;
    __syncthreads();

    for (int off = 1; off < 1024; off <<= 1) {
        int v   = sdata[t];
        int add = (t >= off) ? sdata[t - off] : 0;
        __syncthreads();
        sdata[t] = v + add;
        __syncthreads();
    }
    int run = (t == 0) ? 0 : sdata[t - 1];

    for (int j = 0; j < 64; ++j) {
        int c = row_start[base + j];
        row_start[base + j] = run;
        fill_pos[base + j]  = run;
        run += c;
    }
    if (t == 1023) row_start[NODES_C] = run;  // == E
}

// ---------------------------------------------------------------------------
// Kernel 3: compute w[e] = dot(dist,coeffs) and scatter packed {src,w} into
// CSR order (by dst). One 8B store per edge.
__global__ __launch_bounds__(256) void k_scatter(
    const int* __restrict__ src, const int* __restrict__ dst,
    const float* __restrict__ dist, const float* __restrict__ coeffs,
    int* __restrict__ fill_pos, u64* __restrict__ csr)
{
    int e = blockIdx.x * 256 + threadIdx.x;
    float c0 = coeffs[0], c1 = coeffs[1], c2 = coeffs[2], c3 = coeffs[3], c4 = coeffs[4];
    const float* d = dist + (size_t)e * K_C;
    float wv = d[0]*c0 + d[1]*c1 + d[2]*c2 + d[3]*c3 + d[4]*c4;
    int p = atomicAdd(&fill_pos[dst[e]], 1);
    u64 packed = ((u64)__float_as_uint(wv) << 32) | (unsigned)src[e];
    csr[p] = packed;
}

// ---------------------------------------------------------------------------
// Kernel 4: transpose input x [B][N] -> node-major x0 [N][B]
__global__ __launch_bounds__(256) void k_transpose(
    const float* __restrict__ x_in, float* __restrict__ x_node)
{
    int tid = blockIdx.x * 256 + threadIdx.x;   // tid = b*N + n
    int b = tid >> 16;                          // N = 65536 = 2^16
    int n = tid & 0xFFFF;
    x_node[((size_t)n << 4) + b] = x_in[tid];
}

// ---------------------------------------------------------------------------
// Kernel 5: one explicit-Euler step.
// thread = (node, quad q): handles batches 4q..4q+3 as a float4 accumulator.
// Row loop unrolled x8: 8 meta loads then 8 independent float4 gathers in
// flight per thread. Tail masked (w=0), src clamped so over-read is harmless.
__global__ __launch_bounds__(256) void k_step(
    const int* __restrict__ row_start, const u64* __restrict__ csr,
    const float* __restrict__ x_cur, float* __restrict__ x_next,
    float* __restrict__ out, const float* __restrict__ dt_p,
    size_t TN, int tstep)
{
    __shared__ float tile[64][17];
    int tid = blockIdx.x * 256 + threadIdx.x;
    int n = tid >> 2;
    int q = tid & 3;

    int r0 = row_start[n];
    int r1 = row_start[n + 1];
    float ax = 0.f, ay = 0.f, az = 0.f, aw = 0.f;
    const float* xq = x_cur + (q << 2);

    for (int i = r0; i < r1; i += 8) {
        u64 m[8];
        #pragma unroll
        for (int j = 0; j < 8; ++j) m[j] = csr[i + j];

        float wv[8];
        float4 v[8];
        #pragma unroll
        for (int j = 0; j < 8; ++j) {
            int s = ((int)(unsigned)m[j]) & 0xFFFF;          // clamp: safe gather
            wv[j] = (i + j < r1) ? __uint_as_float((unsigned)(m[j] >> 32)) : 0.f;
            v[j] = *(const float4*)(xq + ((size_t)s << 4));
        }
        #pragma unroll
        for (int j = 0; j < 8; ++j) {
            ax = fmaf(wv[j], v[j].x, ax);
            ay = fmaf(wv[j], v[j].y, ay);
            az = fmaf(wv[j], v[j].z, az);
            aw = fmaf(wv[j], v[j].w, aw);
        }
    }

    float dt = dt_p[0];
    float4 xo = *(const float4*)(x_cur + (((size_t)n) << 4) + (q << 2));
    xo.x = fmaf(dt, ax, xo.x);
    xo.y = fmaf(dt, ay, xo.y);
    xo.z = fmaf(dt, az, xo.z);
    xo.w = fmaf(dt, aw, xo.w);
    *(float4*)(x_next + (((size_t)n) << 4) + (q << 2)) = xo;

    // LDS transpose: 64 nodes x 16 batches -> coalesced out writes
    int ln = threadIdx.x >> 2;            // local node 0..63
    int c0i = q << 2;
    tile[ln][c0i + 0] = xo.x;
    tile[ln][c0i + 1] = xo.y;
    tile[ln][c0i + 2] = xo.z;
    tile[ln][c0i + 3] = xo.w;
    __syncthreads();
    int wb  = threadIdx.x >> 4;           // batch 0..15
    int wn0 = (threadIdx.x & 15) << 2;    // local node 0,4,..,60
    int n0  = blockIdx.x * 64;
    float4 ov;
    ov.x = tile[wn0 + 0][wb];
    ov.y = tile[wn0 + 1][wb];
    ov.z = tile[wn0 + 2][wb];
    ov.w = tile[wn0 + 3][wb];
    *(float4*)(out + (size_t)wb * TN + (size_t)tstep * NODES_C + n0 + wn0) = ov;
}

// ---------------------------------------------------------------------------
extern "C" void kernel_launch(void* const* d_in, const int* in_sizes, int n_in,
                              void* d_out, int out_size, void* d_ws, size_t ws_size,
                              hipStream_t stream)
{
    const float* x_in   = (const float*)d_in[0];
    // d_in[1] = points (unused by the reference computation)
    const int*   eidx   = (const int*)d_in[2];
    const float* dt_p   = (const float*)d_in[3];
    // d_in[4] = num_blocks (T derived from out_size instead)
    const float* dist   = (const float*)d_in[5];
    const float* coeffs = (const float*)d_in[6];

    const int* src = eidx;          // edge_index[0]
    const int* dst = eidx + E_C;    // edge_index[1]
    float* out = (float*)d_out;

    // workspace layout (~17 MB)
    char* ws = (char*)d_ws;
    int*   row_start = (int*)(ws + 0);                    // 256 KB + 4
    int*   fill_pos  = (int*)(ws + (512u << 10));         // 256 KB
    u64*   csr       = (u64*)(ws + (1u  << 20));          // 8 MB (+ over-read slop into x0: masked)
    float* x0        = (float*)(ws + (9u  << 20));        // 4 MB
    float* x1        = (float*)(ws + (13u << 20));        // 4 MB

    int T = out_size / (B_C * NODES_C);          // = 20
    size_t TN = (size_t)T * NODES_C;

    hipMemsetAsync(row_start, 0, (NODES_C + 1) * sizeof(int), stream);
    k_count  <<<E_C / 256, 256, 0, stream>>>(dst, row_start);
    k_scan   <<<1, 1024, 0, stream>>>(row_start, fill_pos);
    k_scatter<<<E_C / 256, 256, 0, stream>>>(src, dst, dist, coeffs, fill_pos, csr);
    k_transpose<<<(NODES_C * B_C) / 256, 256, 0, stream>>>(x_in, x0);

    float* bufs[2] = { x0, x1 };
    for (int t = 0; t < T; ++t) {
        k_step<<<(NODES_C * B_C / 4) / 256, 256, 0, stream>>>(
            row_start, csr, bufs[t & 1], bufs[(t + 1) & 1],
            out, dt_p, TN, t);
    }
}

// Round 5
// 408.945 us; speedup vs baseline: 1.9822x; 1.0588x over previous
//
#include <hip/hip_runtime.h>

// Problem constants (fixed by the reference file)
#define NODES_C 65536   // N*N, N=256
#define B_C     16
#define E_C     1048576 // NODES*16
#define K_C     5

// LDS CSR-segment capacity per 64-node block (entries). Segment length is
// ~Poisson(1024) (sigma~32) -> 2048 is astronomically safe; global fallback kept.
#define MAXE    2048

typedef unsigned long long u64;

// ---------------------------------------------------------------------------
// Kernel 1: histogram of dst
__global__ __launch_bounds__(256) void k_count(
    const int* __restrict__ dst, int* __restrict__ counts)
{
    int e = blockIdx.x * 256 + threadIdx.x;
    atomicAdd(&counts[dst[e]], 1);
}

// ---------------------------------------------------------------------------
// Kernel 2: single-block exclusive prefix sum over counts[NODES] -> row_start
__global__ __launch_bounds__(1024) void k_scan(
    int* __restrict__ row_start /* counts in, exclusive prefix out */,
    int* __restrict__ fill_pos)
{
    __shared__ int sdata[1024];
    int t = threadIdx.x;
    int base = t * 64;

    int s = 0;
    for (int j = 0; j < 64; ++j) s += row_start[base + j];
    sdata[t] = s;
    __syncthreads();

    for (int off = 1; off < 1024; off <<= 1) {
        int v   = sdata[t];
        int add = (t >= off) ? sdata[t - off] : 0;
        __syncthreads();
        sdata[t] = v + add;
        __syncthreads();
    }
    int run = (t == 0) ? 0 : sdata[t - 1];

    for (int j = 0; j < 64; ++j) {
        int c = row_start[base + j];
        row_start[base + j] = run;
        fill_pos[base + j]  = run;
        run += c;
    }
    if (t == 1023) row_start[NODES_C] = run;  // == E
}

// ---------------------------------------------------------------------------
// Kernel 3: compute w[e] = dot(dist,coeffs) and scatter packed {src,w} into
// CSR order (by dst). One 8B store per edge.
__global__ __launch_bounds__(256) void k_scatter(
    const int* __restrict__ src, const int* __restrict__ dst,
    const float* __restrict__ dist, const float* __restrict__ coeffs,
    int* __restrict__ fill_pos, u64* __restrict__ csr)
{
    int e = blockIdx.x * 256 + threadIdx.x;
    float c0 = coeffs[0], c1 = coeffs[1], c2 = coeffs[2], c3 = coeffs[3], c4 = coeffs[4];
    const float* d = dist + (size_t)e * K_C;
    float wv = d[0]*c0 + d[1]*c1 + d[2]*c2 + d[3]*c3 + d[4]*c4;
    int p = atomicAdd(&fill_pos[dst[e]], 1);
    u64 packed = ((u64)__float_as_uint(wv) << 32) | (unsigned)src[e];
    csr[p] = packed;
}

// ---------------------------------------------------------------------------
// Kernel 4: transpose input x [B][N] -> node-major x0 [N][B]
__global__ __launch_bounds__(256) void k_transpose(
    const float* __restrict__ x_in, float* __restrict__ x_node)
{
    int tid = blockIdx.x * 256 + threadIdx.x;   // tid = b*N + n
    int b = tid >> 16;                          // N = 65536 = 2^16
    int n = tid & 0xFFFF;
    x_node[((size_t)n << 4) + b] = x_in[tid];
}

// ---------------------------------------------------------------------------
// Kernel 5: one explicit-Euler step.
// Block = 64 nodes. The block's CSR segment is staged into LDS first with
// coalesced INDEPENDENT loads (no dependent chain), then the row loop reads
// meta from LDS (~free) and issues only the x float4 gathers to global.
// thread = (node, quad q) owning batches 4q..4q+3; unroll x8.
__global__ __launch_bounds__(256) void k_step(
    const int* __restrict__ row_start, const u64* __restrict__ csr,
    const float* __restrict__ x_cur, float* __restrict__ x_next,
    float* __restrict__ out, const float* __restrict__ dt_p,
    size_t TN, int tstep)
{
    __shared__ u64 meta[MAXE + 8];
    __shared__ int rows[65];
    __shared__ float tile[64][17];

    int tid = threadIdx.x;
    int n0  = blockIdx.x * 64;

    int seg0   = row_start[n0];
    int segLen = row_start[n0 + 64] - seg0;
    if (tid < 65) rows[tid] = row_start[n0 + tid];
    bool lds_ok = (segLen <= MAXE);
    if (lds_ok) {
        for (int i = tid; i < segLen; i += 256) meta[i] = csr[seg0 + i];
        if (tid < 8) meta[segLen + tid] = 0;   // zero pad for the tail over-read
    }
    __syncthreads();

    int ln = tid >> 2;            // local node 0..63
    int q  = tid & 3;             // batch quad
    int n  = n0 + ln;
    int r0 = rows[ln]     - seg0; // relative to segment
    int r1 = rows[ln + 1] - seg0;

    float ax = 0.f, ay = 0.f, az = 0.f, aw = 0.f;
    const float* xq = x_cur + (q << 2);

    if (lds_ok) {
        for (int i = r0; i < r1; i += 8) {
            float wv[8];
            float4 v[8];
            #pragma unroll
            for (int j = 0; j < 8; ++j) {
                u64 m = meta[i + j];                     // LDS
                int s = ((int)(unsigned)m) & 0xFFFF;
                wv[j] = (i + j < r1) ? __uint_as_float((unsigned)(m >> 32)) : 0.f;
                v[j]  = *(const float4*)(xq + ((size_t)s << 4));
            }
            #pragma unroll
            for (int j = 0; j < 8; ++j) {
                ax = fmaf(wv[j], v[j].x, ax);
                ay = fmaf(wv[j], v[j].y, ay);
                az = fmaf(wv[j], v[j].z, az);
                aw = fmaf(wv[j], v[j].w, aw);
            }
        }
    } else {
        for (int i = r0; i < r1; i += 8) {
            u64 m[8];
            #pragma unroll
            for (int j = 0; j < 8; ++j) m[j] = csr[seg0 + i + j];
            float wv[8];
            float4 v[8];
            #pragma unroll
            for (int j = 0; j < 8; ++j) {
                int s = ((int)(unsigned)m[j]) & 0xFFFF;
                wv[j] = (i + j < r1) ? __uint_as_float((unsigned)(m[j] >> 32)) : 0.f;
                v[j]  = *(const float4*)(xq + ((size_t)s << 4));
            }
            #pragma unroll
            for (int j = 0; j < 8; ++j) {
                ax = fmaf(wv[j], v[j].x, ax);
                ay = fmaf(wv[j], v[j].y, ay);
                az = fmaf(wv[j], v[j].z, az);
                aw = fmaf(wv[j], v[j].w, aw);
            }
        }
    }

    float dt = dt_p[0];
    float4 xo = *(const float4*)(x_cur + (((size_t)n) << 4) + (q << 2));
    xo.x = fmaf(dt, ax, xo.x);
    xo.y = fmaf(dt, ay, xo.y);
    xo.z = fmaf(dt, az, xo.z);
    xo.w = fmaf(dt, aw, xo.w);
    *(float4*)(x_next + (((size_t)n) << 4) + (q << 2)) = xo;

    // LDS transpose: 64 nodes x 16 batches -> coalesced out writes
    int c0i = q << 2;
    tile[ln][c0i + 0] = xo.x;
    tile[ln][c0i + 1] = xo.y;
    tile[ln][c0i + 2] = xo.z;
    tile[ln][c0i + 3] = xo.w;
    __syncthreads();
    int wb  = tid >> 4;               // batch 0..15
    int wn0 = (tid & 15) << 2;        // local node 0,4,..,60
    float4 ov;
    ov.x = tile[wn0 + 0][wb];
    ov.y = tile[wn0 + 1][wb];
    ov.z = tile[wn0 + 2][wb];
    ov.w = tile[wn0 + 3][wb];
    *(float4*)(out + (size_t)wb * TN + (size_t)tstep * NODES_C + n0 + wn0) = ov;
}

// ---------------------------------------------------------------------------
extern "C" void kernel_launch(void* const* d_in, const int* in_sizes, int n_in,
                              void* d_out, int out_size, void* d_ws, size_t ws_size,
                              hipStream_t stream)
{
    const float* x_in   = (const float*)d_in[0];
    // d_in[1] = points (unused by the reference computation)
    const int*   eidx   = (const int*)d_in[2];
    const float* dt_p   = (const float*)d_in[3];
    // d_in[4] = num_blocks (T derived from out_size instead)
    const float* dist   = (const float*)d_in[5];
    const float* coeffs = (const float*)d_in[6];

    const int* src = eidx;          // edge_index[0]
    const int* dst = eidx + E_C;    // edge_index[1]
    float* out = (float*)d_out;

    // workspace layout (~17 MB)
    char* ws = (char*)d_ws;
    int*   row_start = (int*)(ws + 0);                    // 256 KB + 4
    int*   fill_pos  = (int*)(ws + (512u << 10));         // 256 KB
    u64*   csr       = (u64*)(ws + (1u  << 20));          // 8 MB (+ over-read slop: masked)
    float* x0        = (float*)(ws + (9u  << 20));        // 4 MB
    float* x1        = (float*)(ws + (13u << 20));        // 4 MB

    int T = out_size / (B_C * NODES_C);          // = 20
    size_t TN = (size_t)T * NODES_C;

    hipMemsetAsync(row_start, 0, (NODES_C + 1) * sizeof(int), stream);
    k_count  <<<E_C / 256, 256, 0, stream>>>(dst, row_start);
    k_scan   <<<1, 1024, 0, stream>>>(row_start, fill_pos);
    k_scatter<<<E_C / 256, 256, 0, stream>>>(src, dst, dist, coeffs, fill_pos, csr);
    k_transpose<<<(NODES_C * B_C) / 256, 256, 0, stream>>>(x_in, x0);

    float* bufs[2] = { x0, x1 };
    for (int t = 0; t < T; ++t) {
        k_step<<<(NODES_C * B_C / 4) / 256, 256, 0, stream>>>(
            row_start, csr, bufs[t & 1], bufs[(t + 1) & 1],
            out, dt_p, TN, t);
    }
}

// Round 6
// 387.382 us; speedup vs baseline: 2.0925x; 1.0557x over previous
//
#include <hip/hip_runtime.h>

// Problem constants (fixed by the reference file)
#define NODES_C 65536   // N*N, N=256
#define B_C     16
#define E_C     1048576 // NODES*16
#define K_C     5

// LDS CSR-segment capacity per 64-node block (entries).
#define MAXE    2048

typedef unsigned long long u64;

__device__ inline unsigned short f2bf(float f) {   // RNE float->bf16
    unsigned u = __float_as_uint(f);
    u += 0x7FFFu + ((u >> 16) & 1u);
    return (unsigned short)(u >> 16);
}

// ---------------------------------------------------------------------------
// Kernel 1: histogram of dst
__global__ __launch_bounds__(256) void k_count(
    const int* __restrict__ dst, int* __restrict__ counts)
{
    int e = blockIdx.x * 256 + threadIdx.x;
    atomicAdd(&counts[dst[e]], 1);
}

// ---------------------------------------------------------------------------
// Kernel 2: single-block exclusive prefix sum over counts[NODES] -> row_start
__global__ __launch_bounds__(1024) void k_scan(
    int* __restrict__ row_start, int* __restrict__ fill_pos)
{
    __shared__ int sdata[1024];
    int t = threadIdx.x;
    int base = t * 64;

    int s = 0;
    for (int j = 0; j < 64; ++j) s += row_start[base + j];
    sdata[t] = s;
    __syncthreads();

    for (int off = 1; off < 1024; off <<= 1) {
        int v   = sdata[t];
        int add = (t >= off) ? sdata[t - off] : 0;
        __syncthreads();
        sdata[t] = v + add;
        __syncthreads();
    }
    int run = (t == 0) ? 0 : sdata[t - 1];

    for (int j = 0; j < 64; ++j) {
        int c = row_start[base + j];
        row_start[base + j] = run;
        fill_pos[base + j]  = run;
        run += c;
    }
    if (t == 1023) row_start[NODES_C] = run;  // == E
}

// ---------------------------------------------------------------------------
// Kernel 3: w[e] = dot(dist,coeffs), scatter packed {src,w} into CSR-by-dst.
__global__ __launch_bounds__(256) void k_scatter(
    const int* __restrict__ src, const int* __restrict__ dst,
    const float* __restrict__ dist, const float* __restrict__ coeffs,
    int* __restrict__ fill_pos, u64* __restrict__ csr)
{
    int e = blockIdx.x * 256 + threadIdx.x;
    float c0 = coeffs[0], c1 = coeffs[1], c2 = coeffs[2], c3 = coeffs[3], c4 = coeffs[4];
    const float* d = dist + (size_t)e * K_C;
    float wv = d[0]*c0 + d[1]*c1 + d[2]*c2 + d[3]*c3 + d[4]*c4;
    int p = atomicAdd(&fill_pos[dst[e]], 1);
    u64 packed = ((u64)__float_as_uint(wv) << 32) | (unsigned)src[e];
    csr[p] = packed;
}

// ---------------------------------------------------------------------------
// Kernel 4: init node-major f32 state + bf16 gather mirror
__global__ __launch_bounds__(256) void k_init(
    const float* __restrict__ x_in, float* __restrict__ xf,
    unsigned short* __restrict__ xb)
{
    int tid = blockIdx.x * 256 + threadIdx.x;   // tid = b*N + n
    int b = tid >> 16;                          // N = 65536 = 2^16
    int n = tid & 0xFFFF;
    float v = x_in[tid];
    xf[((size_t)n << 4) + b] = v;
    xb[((size_t)n << 4) + b] = f2bf(v);
}

// ---------------------------------------------------------------------------
// Kernel 5: one explicit-Euler step.
// Gathers read the bf16 mirror (32 B/edge line). f32 state xf is touched only
// by its owning thread (read+write in place, no ping-pong). bf16 mirror is
// ping-ponged across steps. Block = 64 nodes; thread = (node, quad).
__global__ __launch_bounds__(256) void k_step(
    const int* __restrict__ row_start, const u64* __restrict__ csr,
    float* __restrict__ xf, const unsigned short* __restrict__ xbc,
    unsigned short* __restrict__ xbn, float* __restrict__ out,
    const float* __restrict__ dt_p, size_t TN, int tstep)
{
    __shared__ u64 meta[MAXE + 8];
    __shared__ int rows[65];
    __shared__ float tile[64][17];

    int tid = threadIdx.x;
    int n0  = blockIdx.x * 64;

    int seg0   = row_start[n0];
    int segLen = row_start[n0 + 64] - seg0;
    if (tid < 65) rows[tid] = row_start[n0 + tid];
    bool lds_ok = (segLen <= MAXE);
    if (lds_ok) {
        for (int i = tid; i < segLen; i += 256) meta[i] = csr[seg0 + i];
        if (tid < 8) meta[segLen + tid] = 0;   // zero pad for the tail over-read
    }
    __syncthreads();

    int ln = tid >> 2;            // local node 0..63
    int q  = tid & 3;             // batch quad
    int n  = n0 + ln;
    int r0 = rows[ln]     - seg0;
    int r1 = rows[ln + 1] - seg0;

    float ax = 0.f, ay = 0.f, az = 0.f, aw = 0.f;
    const unsigned short* xq = xbc + (q << 2);

    if (lds_ok) {
        for (int i = r0; i < r1; i += 8) {
            float wv[8];
            uint2 rv[8];
            #pragma unroll
            for (int j = 0; j < 8; ++j) {
                u64 m = meta[i + j];                     // LDS
                int s = ((int)(unsigned)m) & 0xFFFF;
                wv[j] = (i + j < r1) ? __uint_as_float((unsigned)(m >> 32)) : 0.f;
                rv[j] = *(const uint2*)(xq + ((size_t)s << 4));
            }
            #pragma unroll
            for (int j = 0; j < 8; ++j) {
                float v0 = __uint_as_float(rv[j].x << 16);
                float v1 = __uint_as_float(rv[j].x & 0xFFFF0000u);
                float v2 = __uint_as_float(rv[j].y << 16);
                float v3 = __uint_as_float(rv[j].y & 0xFFFF0000u);
                ax = fmaf(wv[j], v0, ax);
                ay = fmaf(wv[j], v1, ay);
                az = fmaf(wv[j], v2, az);
                aw = fmaf(wv[j], v3, aw);
            }
        }
    } else {
        for (int i = r0; i < r1; i += 8) {
            u64 m[8];
            #pragma unroll
            for (int j = 0; j < 8; ++j) m[j] = csr[seg0 + i + j];
            float wv[8];
            uint2 rv[8];
            #pragma unroll
            for (int j = 0; j < 8; ++j) {
                int s = ((int)(unsigned)m[j]) & 0xFFFF;
                wv[j] = (i + j < r1) ? __uint_as_float((unsigned)(m[j] >> 32)) : 0.f;
                rv[j] = *(const uint2*)(xq + ((size_t)s << 4));
            }
            #pragma unroll
            for (int j = 0; j < 8; ++j) {
                float v0 = __uint_as_float(rv[j].x << 16);
                float v1 = __uint_as_float(rv[j].x & 0xFFFF0000u);
                float v2 = __uint_as_float(rv[j].y << 16);
                float v3 = __uint_as_float(rv[j].y & 0xFFFF0000u);
                ax = fmaf(wv[j], v0, ax);
                ay = fmaf(wv[j], v1, ay);
                az = fmaf(wv[j], v2, az);
                aw = fmaf(wv[j], v3, aw);
            }
        }
    }

    float dt = dt_p[0];
    size_t own = (((size_t)n) << 4) + (q << 2);
    float4 xo = *(const float4*)(xf + own);
    xo.x = fmaf(dt, ax, xo.x);
    xo.y = fmaf(dt, ay, xo.y);
    xo.z = fmaf(dt, az, xo.z);
    xo.w = fmaf(dt, aw, xo.w);
    *(float4*)(xf + own) = xo;

    ushort4 pk;
    pk.x = f2bf(xo.x); pk.y = f2bf(xo.y); pk.z = f2bf(xo.z); pk.w = f2bf(xo.w);
    *(ushort4*)(xbn + own) = pk;

    // LDS transpose: 64 nodes x 16 batches -> coalesced out writes
    int c0i = q << 2;
    tile[ln][c0i + 0] = xo.x;
    tile[ln][c0i + 1] = xo.y;
    tile[ln][c0i + 2] = xo.z;
    tile[ln][c0i + 3] = xo.w;
    __syncthreads();
    int wb  = tid >> 4;               // batch 0..15
    int wn0 = (tid & 15) << 2;        // local node 0,4,..,60
    float4 ov;
    ov.x = tile[wn0 + 0][wb];
    ov.y = tile[wn0 + 1][wb];
    ov.z = tile[wn0 + 2][wb];
    ov.w = tile[wn0 + 3][wb];
    *(float4*)(out + (size_t)wb * TN + (size_t)tstep * NODES_C + n0 + wn0) = ov;
}

// ---------------------------------------------------------------------------
extern "C" void kernel_launch(void* const* d_in, const int* in_sizes, int n_in,
                              void* d_out, int out_size, void* d_ws, size_t ws_size,
                              hipStream_t stream)
{
    const float* x_in   = (const float*)d_in[0];
    // d_in[1] = points (unused by the reference computation)
    const int*   eidx   = (const int*)d_in[2];
    const float* dt_p   = (const float*)d_in[3];
    // d_in[4] = num_blocks (T derived from out_size instead)
    const float* dist   = (const float*)d_in[5];
    const float* coeffs = (const float*)d_in[6];

    const int* src = eidx;          // edge_index[0]
    const int* dst = eidx + E_C;    // edge_index[1]
    float* out = (float*)d_out;

    // workspace layout (~17 MB)
    char* ws = (char*)d_ws;
    int*   row_start = (int*)(ws + 0);                     // 256 KB + 4
    int*   fill_pos  = (int*)(ws + (512u << 10));          // 256 KB
    u64*   csr       = (u64*)(ws + (1u  << 20));           // 8 MB
    float* xf        = (float*)(ws + (9u  << 20));         // 4 MB f32 state
    unsigned short* xb0 = (unsigned short*)(ws + (13u << 20)); // 2 MB bf16 mirror
    unsigned short* xb1 = (unsigned short*)(ws + (15u << 20)); // 2 MB bf16 mirror

    int T = out_size / (B_C * NODES_C);          // = 20
    size_t TN = (size_t)T * NODES_C;

    hipMemsetAsync(row_start, 0, (NODES_C + 1) * sizeof(int), stream);
    k_count  <<<E_C / 256, 256, 0, stream>>>(dst, row_start);
    k_scan   <<<1, 1024, 0, stream>>>(row_start, fill_pos);
    k_scatter<<<E_C / 256, 256, 0, stream>>>(src, dst, dist, coeffs, fill_pos, csr);
    k_init   <<<(NODES_C * B_C) / 256, 256, 0, stream>>>(x_in, xf, xb0);

    unsigned short* xbufs[2] = { xb0, xb1 };
    for (int t = 0; t < T; ++t) {
        k_step<<<(NODES_C * B_C / 4) / 256, 256, 0, stream>>>(
            row_start, csr, xf, xbufs[t & 1], xbufs[(t + 1) & 1],
            out, dt_p, TN, t);
    }
}

// Round 7
// 329.720 us; speedup vs baseline: 2.4584x; 1.1749x over previous
//
#include <hip/hip_runtime.h>

// Problem constants (fixed by the reference file)
#define NODES_C 65536   // N*N, N=256
#define B_C     16
#define E_C     1048576 // NODES*16
#define K_C     5

#define MAXE    2048    // LDS CSR-segment cap per 64-node step block
#define CAP_D   8192    // per-bucket LDS cap in k_sortb (avg 4096, 50+ sigma safe)

typedef unsigned long long u64;

__device__ inline unsigned short f2bf(float f) {   // RNE float->bf16
    unsigned u = __float_as_uint(f);
    u += 0x7FFFu + ((u >> 16) & 1u);
    return (unsigned short)(u >> 16);
}

// ---------------------------------------------------------------------------
// Build kernel A: 256-bin histogram of dst>>8
__global__ __launch_bounds__(256) void k_hist(
    const int* __restrict__ dst, int* __restrict__ hist)
{
    __shared__ int h[256];
    int tid = threadIdx.x;
    h[tid] = 0;
    __syncthreads();
    int e0 = blockIdx.x * 1024;
    #pragma unroll
    for (int j = 0; j < 4; ++j)
        atomicAdd(&h[((unsigned)dst[e0 + j * 256 + tid]) >> 8], 1);
    __syncthreads();
    atomicAdd(&hist[tid], h[tid]);
}

// ---------------------------------------------------------------------------
// Build kernel B: exclusive scan of hist256 -> base, fill
__global__ __launch_bounds__(256) void k_scan256(
    const int* __restrict__ hist, int* __restrict__ base, int* __restrict__ fill)
{
    __shared__ int s[256];
    int t = threadIdx.x;
    s[t] = hist[t];
    __syncthreads();
    for (int off = 1; off < 256; off <<= 1) {
        int v = s[t];
        int a = (t >= off) ? s[t - off] : 0;
        __syncthreads();
        s[t] = v + a;
        __syncthreads();
    }
    int ex = (t == 0) ? 0 : s[t - 1];
    base[t] = ex;
    fill[t] = ex;
}

// ---------------------------------------------------------------------------
// Build kernel C: compute w, pack {w | dst&255 | src}, bucket by dst>>8 into
// csr (bucket-clustered, run-contiguous writes). 256 blocks x 4096 edges.
__global__ __launch_bounds__(256) void k_bucket(
    const int* __restrict__ src, const int* __restrict__ dst,
    const float* __restrict__ dist, const float* __restrict__ coeffs,
    int* __restrict__ fill, u64* __restrict__ csr)
{
    __shared__ int hist[256];
    __shared__ int scan[256];
    __shared__ int exs[256];
    __shared__ int gpos[256];
    __shared__ int lfill[256];
    __shared__ u64 stage[4096];

    int tid = threadIdx.x;
    hist[tid] = 0;
    __syncthreads();

    float c0 = coeffs[0], c1 = coeffs[1], c2 = coeffs[2], c3 = coeffs[3], c4 = coeffs[4];
    int e0 = blockIdx.x * 4096;
    u64 pk[16];
    int bk[16];
    #pragma unroll
    for (int j = 0; j < 16; ++j) {
        int e = e0 + j * 256 + tid;
        unsigned s = (unsigned)src[e];
        unsigned d = (unsigned)dst[e];
        const float* dd = dist + (size_t)e * K_C;
        float wv = dd[0]*c0 + dd[1]*c1 + dd[2]*c2 + dd[3]*c3 + dd[4]*c4;
        pk[j] = ((u64)__float_as_uint(wv) << 32) | ((d & 255u) << 16) | s;
        bk[j] = (int)(d >> 8);
        atomicAdd(&hist[bk[j]], 1);
    }
    __syncthreads();

    scan[tid] = hist[tid];
    __syncthreads();
    for (int off = 1; off < 256; off <<= 1) {
        int v = scan[tid];
        int a = (tid >= off) ? scan[tid - off] : 0;
        __syncthreads();
        scan[tid] = v + a;
        __syncthreads();
    }
    exs[tid]   = scan[tid] - hist[tid];               // local exclusive base
    gpos[tid]  = atomicAdd(&fill[tid], hist[tid]);    // absolute run start
    lfill[tid] = 0;
    __syncthreads();

    #pragma unroll
    for (int j = 0; j < 16; ++j) {
        int b = bk[j];
        int p = exs[b] + atomicAdd(&lfill[b], 1);
        stage[p] = pk[j];
    }
    __syncthreads();

    int c = hist[tid], g = gpos[tid], lb = exs[tid];
    for (int i = 0; i < c; ++i) csr[g + i] = stage[lb + i];
}

// ---------------------------------------------------------------------------
// Build kernel D: one block per bucket. In-place counting sort of the bucket
// by dst&255 (LDS), coalesced write-back, emits row_start for its 256 nodes.
__global__ __launch_bounds__(256) void k_sortb(
    const int* __restrict__ base, const int* __restrict__ hist,
    u64* __restrict__ csr, int* __restrict__ row_start)
{
    __shared__ u64 stage[CAP_D];
    __shared__ int h[256];
    __shared__ int sc[256];
    __shared__ int lf[256];

    int b = blockIdx.x, tid = threadIdx.x;
    int b0 = base[b];
    int len = hist[b];

    h[tid] = 0;
    __syncthreads();
    for (int i = tid; i < len; i += 256)
        atomicAdd(&h[(int)((csr[b0 + i] >> 16) & 255u)], 1);
    __syncthreads();

    sc[tid] = h[tid];
    __syncthreads();
    for (int off = 1; off < 256; off <<= 1) {
        int v = sc[tid];
        int a = (tid >= off) ? sc[tid - off] : 0;
        __syncthreads();
        sc[tid] = v + a;
        __syncthreads();
    }
    int ex = sc[tid] - h[tid];
    row_start[b * 256 + tid] = b0 + ex;
    lf[tid] = 0;
    __syncthreads();

    for (int i = tid; i < len; i += 256) {
        u64 m = csr[b0 + i];
        int dl = (int)((m >> 16) & 255u);
        int p = (sc[dl] - h[dl]) + atomicAdd(&lf[dl], 1);
        stage[p] = m;
    }
    __syncthreads();
    for (int i = tid; i < len; i += 256) csr[b0 + i] = stage[i];
    if (b == 255 && tid == 255) row_start[NODES_C] = b0 + len;  // == E
}

// ---------------------------------------------------------------------------
// Kernel: init node-major f32 state + bf16 gather mirror
__global__ __launch_bounds__(256) void k_init(
    const float* __restrict__ x_in, float* __restrict__ xf,
    unsigned short* __restrict__ xb)
{
    int tid = blockIdx.x * 256 + threadIdx.x;   // tid = b*N + n
    int b = tid >> 16;                          // N = 65536 = 2^16
    int n = tid & 0xFFFF;
    float v = x_in[tid];
    xf[((size_t)n << 4) + b] = v;
    xb[((size_t)n << 4) + b] = f2bf(v);
}

// ---------------------------------------------------------------------------
// Step kernel: gathers read the bf16 mirror; f32 state in place; mirror
// ping-ponged. Block = 64 nodes; thread = (node, quad). L2 warmed by a
// per-block prefetch of mirror slice bid>>3 (round-robin bid->XCD assumed;
// wrong mapping only weakens the warm, never breaks correctness).
__global__ __launch_bounds__(256) void k_step(
    const int* __restrict__ row_start, const u64* __restrict__ csr,
    float* __restrict__ xf, const unsigned short* __restrict__ xbc,
    unsigned short* __restrict__ xbn, float* __restrict__ out,
    const float* __restrict__ dt_p, size_t TN, int tstep)
{
    __shared__ u64 meta[MAXE + 8];
    __shared__ int rows[65];
    __shared__ float tile[64][17];

    int tid = threadIdx.x;
    int n0  = blockIdx.x * 64;

    // L2 warm: 16KB slice of the current mirror per block
    {
        const uint4* pf = (const uint4*)xbc + ((size_t)(blockIdx.x >> 3) << 10);
        unsigned acc = 0;
        #pragma unroll
        for (int k = 0; k < 4; ++k) {
            uint4 v = pf[k * 256 + tid];
            acc ^= v.x ^ v.w;
        }
        asm volatile("" :: "v"(acc));   // keep loads alive, no side effect
    }

    int seg0   = row_start[n0];
    int segLen = row_start[n0 + 64] - seg0;
    if (tid < 65) rows[tid] = row_start[n0 + tid];
    bool lds_ok = (segLen <= MAXE);
    if (lds_ok) {
        for (int i = tid; i < segLen; i += 256) meta[i] = csr[seg0 + i];
        if (tid < 8) meta[segLen + tid] = 0;   // zero pad for the tail over-read
    }
    __syncthreads();

    int ln = tid >> 2;            // local node 0..63
    int q  = tid & 3;             // batch quad
    int n  = n0 + ln;
    int r0 = rows[ln]     - seg0;
    int r1 = rows[ln + 1] - seg0;

    float ax = 0.f, ay = 0.f, az = 0.f, aw = 0.f;
    const unsigned short* xq = xbc + (q << 2);

    if (lds_ok) {
        for (int i = r0; i < r1; i += 8) {
            float wv[8];
            uint2 rv[8];
            #pragma unroll
            for (int j = 0; j < 8; ++j) {
                u64 m = meta[i + j];                     // LDS
                int s = ((int)(unsigned)m) & 0xFFFF;
                wv[j] = (i + j < r1) ? __uint_as_float((unsigned)(m >> 32)) : 0.f;
                rv[j] = *(const uint2*)(xq + ((size_t)s << 4));
            }
            #pragma unroll
            for (int j = 0; j < 8; ++j) {
                float v0 = __uint_as_float(rv[j].x << 16);
                float v1 = __uint_as_float(rv[j].x & 0xFFFF0000u);
                float v2 = __uint_as_float(rv[j].y << 16);
                float v3 = __uint_as_float(rv[j].y & 0xFFFF0000u);
                ax = fmaf(wv[j], v0, ax);
                ay = fmaf(wv[j], v1, ay);
                az = fmaf(wv[j], v2, az);
                aw = fmaf(wv[j], v3, aw);
            }
        }
    } else {
        for (int i = r0; i < r1; i += 8) {
            u64 m[8];
            #pragma unroll
            for (int j = 0; j < 8; ++j) m[j] = csr[seg0 + i + j];
            float wv[8];
            uint2 rv[8];
            #pragma unroll
            for (int j = 0; j < 8; ++j) {
                int s = ((int)(unsigned)m[j]) & 0xFFFF;
                wv[j] = (i + j < r1) ? __uint_as_float((unsigned)(m[j] >> 32)) : 0.f;
                rv[j] = *(const uint2*)(xq + ((size_t)s << 4));
            }
            #pragma unroll
            for (int j = 0; j < 8; ++j) {
                float v0 = __uint_as_float(rv[j].x << 16);
                float v1 = __uint_as_float(rv[j].x & 0xFFFF0000u);
                float v2 = __uint_as_float(rv[j].y << 16);
                float v3 = __uint_as_float(rv[j].y & 0xFFFF0000u);
                ax = fmaf(wv[j], v0, ax);
                ay = fmaf(wv[j], v1, ay);
                az = fmaf(wv[j], v2, az);
                aw = fmaf(wv[j], v3, aw);
            }
        }
    }

    float dt = dt_p[0];
    size_t own = (((size_t)n) << 4) + (q << 2);
    float4 xo = *(const float4*)(xf + own);
    xo.x = fmaf(dt, ax, xo.x);
    xo.y = fmaf(dt, ay, xo.y);
    xo.z = fmaf(dt, az, xo.z);
    xo.w = fmaf(dt, aw, xo.w);
    *(float4*)(xf + own) = xo;

    ushort4 pkv;
    pkv.x = f2bf(xo.x); pkv.y = f2bf(xo.y); pkv.z = f2bf(xo.z); pkv.w = f2bf(xo.w);
    *(ushort4*)(xbn + own) = pkv;

    // LDS transpose: 64 nodes x 16 batches -> coalesced out writes
    int c0i = q << 2;
    tile[ln][c0i + 0] = xo.x;
    tile[ln][c0i + 1] = xo.y;
    tile[ln][c0i + 2] = xo.z;
    tile[ln][c0i + 3] = xo.w;
    __syncthreads();
    int wb  = tid >> 4;               // batch 0..15
    int wn0 = (tid & 15) << 2;        // local node 0,4,..,60
    float4 ov;
    ov.x = tile[wn0 + 0][wb];
    ov.y = tile[wn0 + 1][wb];
    ov.z = tile[wn0 + 2][wb];
    ov.w = tile[wn0 + 3][wb];
    *(float4*)(out + (size_t)wb * TN + (size_t)tstep * NODES_C + n0 + wn0) = ov;
}

// ---------------------------------------------------------------------------
extern "C" void kernel_launch(void* const* d_in, const int* in_sizes, int n_in,
                              void* d_out, int out_size, void* d_ws, size_t ws_size,
                              hipStream_t stream)
{
    const float* x_in   = (const float*)d_in[0];
    // d_in[1] = points (unused by the reference computation)
    const int*   eidx   = (const int*)d_in[2];
    const float* dt_p   = (const float*)d_in[3];
    // d_in[4] = num_blocks (T derived from out_size instead)
    const float* dist   = (const float*)d_in[5];
    const float* coeffs = (const float*)d_in[6];

    const int* src = eidx;          // edge_index[0]
    const int* dst = eidx + E_C;    // edge_index[1]
    float* out = (float*)d_out;

    // workspace layout (~17 MB)
    char* ws = (char*)d_ws;
    int*   row_start = (int*)(ws + 0);                     // 256 KB + 4
    int*   hist256   = (int*)(ws + (512u << 10));          // 1 KB
    int*   base256   = (int*)(ws + (516u << 10));          // 1 KB
    int*   fill256   = (int*)(ws + (520u << 10));          // 1 KB
    u64*   csr       = (u64*)(ws + (1u  << 20));           // 8 MB
    float* xf        = (float*)(ws + (9u  << 20));         // 4 MB f32 state
    unsigned short* xb0 = (unsigned short*)(ws + (13u << 20)); // 2 MB bf16 mirror
    unsigned short* xb1 = (unsigned short*)(ws + (15u << 20)); // 2 MB bf16 mirror

    int T = out_size / (B_C * NODES_C);          // = 20
    size_t TN = (size_t)T * NODES_C;

    hipMemsetAsync(hist256, 0, 256 * sizeof(int), stream);
    k_hist   <<<E_C / 1024, 256, 0, stream>>>(dst, hist256);
    k_scan256<<<1, 256, 0, stream>>>(hist256, base256, fill256);
    k_bucket <<<E_C / 4096, 256, 0, stream>>>(src, dst, dist, coeffs, fill256, csr);
    k_sortb  <<<256, 256, 0, stream>>>(base256, hist256, csr, row_start);
    k_init   <<<(NODES_C * B_C) / 256, 256, 0, stream>>>(x_in, xf, xb0);

    unsigned short* xbufs[2] = { xb0, xb1 };
    for (int t = 0; t < T; ++t) {
        k_step<<<(NODES_C * B_C / 4) / 256, 256, 0, stream>>>(
            row_start, csr, xf, xbufs[t & 1], xbufs[(t + 1) & 1],
            out, dt_p, TN, t);
    }
}